// Round 13
// baseline (28.145 us; speedup 1.0000x reference)
//
#include <hip/hip_runtime.h>

#define NQ   10
#define NL   4
#define NCL  10
#define PI_F 3.14159265358979f

typedef float f2 __attribute__((ext_vector_type(2)));

// ---- forced VOP3P packed-f32 (compiler scalarizes <2 x float> otherwise) ----
__device__ __forceinline__ f2 pk_mul2(f2 a, f2 b) {
    f2 d;
    asm("v_pk_mul_f32 %0, %1, %2" : "=v"(d) : "v"(a), "v"(b));
    return d;
}
__device__ __forceinline__ f2 pk_fma2(f2 a, f2 b, f2 c) {   // a*b + c
    f2 d;
    asm("v_pk_fma_f32 %0, %1, %2, %3" : "=v"(d) : "v"(a), "v"(b), "v"(c));
    return d;
}
__device__ __forceinline__ f2 pk_add2(f2 a, f2 b) {
    f2 d;
    asm("v_pk_add_f32 %0, %1, %2" : "=v"(d) : "v"(a), "v"(b));
    return d;
}

// Broadcast lane l's value (uniform l) via v_readlane.
__device__ __forceinline__ float bcastf(float v, int l) {
    return __int_as_float(__builtin_amdgcn_readlane(__float_as_int(v), l));
}

__device__ __forceinline__ float bperm(int byteaddr, float v) {
    return __int_as_float(__builtin_amdgcn_ds_bpermute(byteaddr, __float_as_int(v)));
}

// Cross-lane xor-butterfly fetch: DPP / ds_swizzle / permlane_swap (validated R5-R11).
template<int M>
__device__ __forceinline__ float xlane(float v) {
    if constexpr (M == 1) {        // quad_perm [1,0,3,2]
        return __int_as_float(__builtin_amdgcn_update_dpp(
            __float_as_int(v), __float_as_int(v), 0xB1, 0xF, 0xF, false));
    } else if constexpr (M == 2) { // quad_perm [2,3,0,1]
        return __int_as_float(__builtin_amdgcn_update_dpp(
            __float_as_int(v), __float_as_int(v), 0x4E, 0xF, 0xF, false));
    } else if constexpr (M == 4) { // ds_swizzle xor-4 imm pattern
        return __int_as_float(__builtin_amdgcn_ds_swizzle(
            __float_as_int(v), 0x101F));
    } else if constexpr (M == 8) { // row_ror:8 == xor-8 within 16-lane rows
        return __int_as_float(__builtin_amdgcn_update_dpp(
            __float_as_int(v), __float_as_int(v), 0x128, 0xF, 0xF, false));
    } else if constexpr (M == 16) {
        // direction-proof: exactly one of the two results is bitwise-own per lane
        auto r = __builtin_amdgcn_permlane16_swap(
            (unsigned)__float_as_int(v), (unsigned)__float_as_int(v), false, false);
        return __int_as_float((int)(r[0] ^ r[1] ^ (unsigned)__float_as_int(v)));
    } else {                       // M == 32
        auto r = __builtin_amdgcn_permlane32_swap(
            (unsigned)__float_as_int(v), (unsigned)__float_as_int(v), false, false);
        return __int_as_float((int)(r[0] ^ r[1] ^ (unsigned)__float_as_int(v)));
    }
}

template<int M>
__device__ __forceinline__ f2 xlane2(f2 v) {
    f2 r; r.x = xlane<M>(v.x); r.y = xlane<M>(v.y); return r;
}

// RY on a lane-bit wire (packed): sc' = se*partner + c*sc.
template<int M>
__device__ __forceinline__ void xwire2(float c, float s, int lane, f2 (&sc)[16]) {
    const float se = (lane & M) ? s : -s;
    const f2 c2 = {c, c}, se2 = {se, se};
    #pragma unroll
    for (int r = 0; r < 16; ++r) {
        f2 t = xlane2<M>(sc[r]);
        sc[r] = pk_fma2(se2, t, pk_mul2(c2, sc[r]));
    }
}

// Full-wave butterfly sum, packed pair.
__device__ __forceinline__ f2 bsum2(f2 v) {
    v = pk_add2(v, xlane2<1 >(v));
    v = pk_add2(v, xlane2<2 >(v));
    v = pk_add2(v, xlane2<4 >(v));
    v = pk_add2(v, xlane2<8 >(v));
    v = pk_add2(v, xlane2<16>(v));
    v = pk_add2(v, xlane2<32>(v));
    return v;
}

// Layout: one wave per batch element. Lane l holds amplitudes d = (l<<4)|r
// as f2{re,im}: register bits = qubits 0..3, lane bits = qubits 4..9.
__global__ __launch_bounds__(256)
void qnn_kernel(const float* __restrict__ x,
                const float* __restrict__ W_pre,
                const float* __restrict__ b_pre,
                const float* __restrict__ weights,
                const float* __restrict__ W_post,
                const float* __restrict__ b_post,
                float* __restrict__ out, int batch)
{
    const int lane = threadIdx.x & 63;
    const int b = blockIdx.x * 4 + (threadIdx.x >> 6);
    if (b >= batch) return;
    const int bu = __builtin_amdgcn_readfirstlane(b);   // wave-uniform

    // 50 half-angle cos/sin pairs: lane j<50 owns weight j.
    float cw = 0.0f, sw = 0.0f;
    if (lane < (NL + 1) * NQ) {
        float th = 0.5f * weights[lane];
        __sincosf(th, &sw, &cw);
    }

    // h = x @ W_pre.T + b_pre : all lanes, uniform addresses.
    float xv[NQ];
    #pragma unroll
    for (int k = 0; k < NQ; ++k) xv[k] = x[bu * NQ + k];
    float h[NQ];
    #pragma unroll
    for (int j = 0; j < NQ; ++j) {
        float acc = b_pre[j];
        #pragma unroll
        for (int k = 0; k < NQ; ++k)
            acc = fmaf(xv[k], W_pre[j * NQ + k], acc);
        h[j] = acc;
    }
    float z[NQ - 1];
    #pragma unroll
    for (int i = 0; i < NQ - 1; ++i) z[i] = (PI_F - h[i]) * (PI_F - h[i + 1]);

    // Lane-constant angle part (qubits 4..9, zz pairs (4,5)..(8,9)).
    float A = 0.0f;
    #pragma unroll
    for (int i = 4; i < NQ; ++i)
        A += ((lane >> (i - 4)) & 1) ? -h[i] : h[i];
    #pragma unroll
    for (int i = 4; i < NQ - 1; ++i)
        A += (((lane >> (i - 4)) ^ (lane >> (i - 3))) & 1) ? -z[i] : z[i];

    // State init: (1/32) e^{-i ang}.
    f2 sc[16];
    #pragma unroll
    for (int r = 0; r < 16; ++r) {
        float ang = A;
        #pragma unroll
        for (int i = 0; i < 4; ++i)
            ang += ((r >> i) & 1) ? -h[i] : h[i];   // r compile-time: add/sub
        #pragma unroll
        for (int i = 0; i < 3; ++i)
            ang += (((r >> i) ^ (r >> (i + 1))) & 1) ? -z[i] : z[i];
        ang += (((r >> 3) ^ lane) & 1) ? -z[3] : z[3];
        float sn, cn;
        __sincosf(ang, &sn, &cn);
        sc[r].x = 0.03125f * cn;
        sc[r].y = -0.03125f * sn;
    }

    // CNOT-chain perm lane part: l' = ((l ^ (l<<1)) & 0x3F) ^ r3.
    const int plbase = (lane ^ (lane << 1)) & 0x3F;
    const int paddr0 = plbase << 2;
    const int paddr1 = (plbase ^ 1) << 2;

    #pragma clang loop unroll(disable)
    for (int l = 0; l <= NL; ++l) {
        if (l > 0) {
            // new[(l,r)] = old[(l', r')], r' = (r ^ (r<<1)) & 0xF
            f2 np[16];
            #pragma unroll
            for (int r = 0; r < 16; ++r) {
                const int rp = (r ^ (r << 1)) & 0xF;
                const int pa = (r < 8) ? paddr0 : paddr1;
                np[r].x = bperm(pa, sc[rp].x);
                np[r].y = bperm(pa, sc[rp].y);
            }
            #pragma unroll
            for (int r = 0; r < 16; ++r) sc[r] = np[r];
        }

        const int base = l * NQ;

        // Wires 0..3: in-register butterflies, forced-packed.
        #pragma unroll
        for (int w = 0; w < 4; ++w) {
            const float c = bcastf(cw, base + w);
            const float s = bcastf(sw, base + w);
            const f2 c2 = {c, c}, s2 = {s, s}, ns2 = {-s, -s};
            #pragma unroll
            for (int r = 0; r < 16; ++r) {
                if (r & (1 << w)) continue;
                const int q = r | (1 << w);
                f2 a0 = sc[r], a1 = sc[q];
                sc[r] = pk_fma2(ns2, a1, pk_mul2(c2, a0));   // c*a0 - s*a1
                sc[q] = pk_fma2(s2,  a0, pk_mul2(c2, a1));   // s*a0 + c*a1
            }
        }

        // Wires 4..9: lane-bit butterflies, forced-packed.
        xwire2<1 >(bcastf(cw, base + 4), bcastf(sw, base + 4), lane, sc);
        xwire2<2 >(bcastf(cw, base + 5), bcastf(sw, base + 5), lane, sc);
        xwire2<4 >(bcastf(cw, base + 6), bcastf(sw, base + 6), lane, sc);
        xwire2<8 >(bcastf(cw, base + 7), bcastf(sw, base + 7), lane, sc);
        xwire2<16>(bcastf(cw, base + 8), bcastf(sw, base + 8), lane, sc);
        xwire2<32>(bcastf(cw, base + 9), bcastf(sw, base + 9), lane, sc);
    }

    // Probabilities and q_k.
    float P = 0.0f, p0 = 0.0f, p1 = 0.0f, p2 = 0.0f, p3 = 0.0f;
    #pragma unroll
    for (int r = 0; r < 16; ++r) {
        f2 qq = pk_mul2(sc[r], sc[r]);
        float pr = qq.x + qq.y;
        P  += pr;
        p0 += (r & 1) ? -pr : pr;
        p1 += (r & 2) ? -pr : pr;
        p2 += (r & 4) ? -pr : pr;
        p3 += (r & 8) ? -pr : pr;
    }
    // q_0..3: packed butterfly sums (all lanes get totals).
    f2 qa = bsum2((f2){p0, p1});
    f2 qb = bsum2((f2){p2, p3});
    // q_4..9: Walsh transform of P over lanes; value at lane 2^j.
    {
        float t;
        t = xlane<1 >(P); P = t + ((lane & 1 ) ? -P : P);
        t = xlane<2 >(P); P = t + ((lane & 2 ) ? -P : P);
        t = xlane<4 >(P); P = t + ((lane & 4 ) ? -P : P);
        t = xlane<8 >(P); P = t + ((lane & 8 ) ? -P : P);
        t = xlane<16>(P); P = t + ((lane & 16) ? -P : P);
        t = xlane<32>(P); P = t + ((lane & 32) ? -P : P);
    }
    float q[NCL];
    q[0] = qa.x; q[1] = qa.y; q[2] = qb.x; q[3] = qb.y;
    q[4] = bcastf(P, 1);
    q[5] = bcastf(P, 2);
    q[6] = bcastf(P, 4);
    q[7] = bcastf(P, 8);
    q[8] = bcastf(P, 16);
    q[9] = bcastf(P, 32);

    if (lane < NCL) {
        float o = b_post[lane];
        #pragma unroll
        for (int k = 0; k < NCL; ++k)
            o = fmaf(q[k], W_post[lane * NQ + k], o);
        out[b * NCL + lane] = o;
    }
}

extern "C" void kernel_launch(void* const* d_in, const int* in_sizes, int n_in,
                              void* d_out, int out_size, void* d_ws, size_t ws_size,
                              hipStream_t stream) {
    const float* x       = (const float*)d_in[0];
    const float* W_pre   = (const float*)d_in[1];
    const float* b_pre   = (const float*)d_in[2];
    const float* weights = (const float*)d_in[3];
    const float* W_post  = (const float*)d_in[4];
    const float* b_post  = (const float*)d_in[5];
    float* outp = (float*)d_out;
    int batch = in_sizes[0] / NQ;
    int grid = (batch + 3) / 4;
    qnn_kernel<<<grid, 256, 0, stream>>>(x, W_pre, b_pre, weights, W_post, b_post, outp, batch);
}